// Round 5
// baseline (156.293 us; speedup 1.0000x reference)
//
#include <hip/hip_runtime.h>

// Problem constants (reference: B=8, N=16384, F=128, P=28)
#define FDIM  128
#define PDIM  28
#define KPAD  896              // 28 p-steps * 32 padded q
#define MPTS  131072           // 8 * 16384 points
#define BSTR  904              // bs k-stride in f16: 904*2=1808 B, 1808/4 mod 32 = 4
                               // -> b128 start bank 4*(ln31+g) mod 32: 8-phase conflict-free

typedef _Float16 half8    __attribute__((ext_vector_type(8)));
typedef _Float16 half4v   __attribute__((ext_vector_type(4)));
typedef float    floatx16 __attribute__((ext_vector_type(16)));

// ---------------------------------------------------------------------------
// prep1: IF [F][28][28] fp32 -> IFt [F][KPAD] f16, k = p*32+q, zero pad q>=28
// ---------------------------------------------------------------------------
__global__ __launch_bounds__(256) void prep_ift(const float* __restrict__ IF,
                                                _Float16* __restrict__ IFt) {
    int idx = blockIdx.x * 256 + threadIdx.x;
    int f = idx / KPAD;
    int k = idx - f * KPAD;
    int p = k >> 5;
    int q = k & 31;
    float v = (q < PDIM) ? IF[f * (PDIM * PDIM) + p * PDIM + q] : 0.0f;
    IFt[idx] = (_Float16)v;
}

// ---------------------------------------------------------------------------
// prep2: k0t [7][MPTS][4] f16  (k0t[p4][pt][i] = k0[pt][p4*4+i])
//        k1t [4][MPTS][8] f16  (k1t[h][pt][j]  = k1[pt][h*8+j], zero q>=28)
// Fragment-ready, fully coalesced reads in the main kernel.
// ---------------------------------------------------------------------------
__global__ __launch_bounds__(256) void prep_k(const float* __restrict__ x,
                                              const float* __restrict__ sigma,
                                              _Float16* __restrict__ k0t,
                                              _Float16* __restrict__ k1t) {
    const int pt = blockIdx.x * 256 + threadIdx.x;      // 0..MPTS-1
    const float ls    = __expf(sigma[0]);
    const float inv   = 0.5f / (ls * ls);
    const float gstep = 0.998f / 27.0f;
    const float x0 = x[2 * pt + 0];
    const float x1 = x[2 * pt + 1];

    _Float16 k0[28], k1[32];
    #pragma unroll
    for (int p = 0; p < PDIM; p++) {
        float d = (0.001f + p * gstep) - x0;
        k0[p] = (_Float16)__expf(-inv * d * d);
    }
    #pragma unroll
    for (int q = 0; q < PDIM; q++) {
        float d = (0.001f + q * gstep) - x1;
        k1[q] = (_Float16)__expf(-inv * d * d);
    }
    #pragma unroll
    for (int q = PDIM; q < 32; q++) k1[q] = (_Float16)0.0f;

    #pragma unroll
    for (int p4 = 0; p4 < 7; p4++) {
        half4v v; 
        #pragma unroll
        for (int i = 0; i < 4; i++) v[i] = k0[p4 * 4 + i];
        *(half4v*)&k0t[((size_t)p4 * MPTS + pt) * 4] = v;
    }
    #pragma unroll
    for (int h = 0; h < 4; h++) {
        half8 v;
        #pragma unroll
        for (int j = 0; j < 8; j++) v[j] = k1[h * 8 + j];
        *(half8*)&k1t[((size_t)h * MPTS + pt) * 8] = v;
    }
}

// ---------------------------------------------------------------------------
// Main: C[m,f] = sum_k W[m,k] * IFt[k,f],  W[m,p*32+q] = k0[m,p]*k1[m,q]
// mfma_f32_32x32x16_f16. Block = 32-feature strip x 1024 points; 4 waves,
// each wave INDEPENDENT: 2 chunks of 128 pts x 32 f (4 m-tiles of 32).
// B strip staged to LDS once (57.8 KB -> 2 blocks/CU = 2 waves/SIMD);
// ONE barrier per block; K-loop is pure ds_read + pk_mul + MFMA.
// All k0/k1 fragment loads issued up-front per chunk (L3-resident, coalesced).
// ---------------------------------------------------------------------------
__global__ __launch_bounds__(256, 2) void feats_kernel(
    const _Float16* __restrict__ IFt,   // [FDIM][KPAD]
    const _Float16* __restrict__ k0t,   // [7][MPTS][4]
    const _Float16* __restrict__ k1t,   // [4][MPTS][8]
    float* __restrict__ out)            // [MPTS][FDIM]
{
    __shared__ __align__(16) _Float16 bs[32 * BSTR];   // 57,856 B

    const int tid  = threadIdx.x;
    const int lane = tid & 63;
    const int wave = tid >> 6;
    const int ln31 = lane & 31;
    const int g    = lane >> 5;          // k-slot group: k = p*32 + qh*16 + g*8 + j

    const int fs    = blockIdx.x & 3;    // 4 feature strips of 32
    const int pg    = blockIdx.x >> 2;   // 0..127: point group of 1024
    const int fbase = fs * 32;

    // ---- stage B strip (32 f x 896 k) into LDS once ----
    {
        const int row = tid >> 3;        // 0..31
        const int seg = tid & 7;         // 8 threads per row, 14 uint4 each
        const uint4* gsrc = (const uint4*)(IFt + (size_t)(fbase + row) * KPAD);
        uint4* ldst = (uint4*)&bs[row * BSTR];
        #pragma unroll
        for (int j = 0; j < 14; j++)
            ldst[seg * 14 + j] = gsrc[seg * 14 + j];
    }
    __syncthreads();    // the only barrier

    const int bfo = ln31 * BSTR + g * 8;   // bf f16 offset base

    #pragma unroll 1
    for (int c = 0; c < 2; c++) {
        const int chunkbase = pg * 1024 + c * 512 + wave * 128;

        // ---- all k0/k1 fragments for this chunk, issued up-front ----
        half4v k0v[4][7];
        half8  k1f[4][2];
        #pragma unroll
        for (int mt = 0; mt < 4; mt++) {
            const int ptr_ = chunkbase + mt * 32 + ln31;
            #pragma unroll
            for (int p4 = 0; p4 < 7; p4++)
                k0v[mt][p4] = *(const half4v*)&k0t[((size_t)p4 * MPTS + ptr_) * 4];
            k1f[mt][0] = *(const half8*)&k1t[((size_t)(0 + g) * MPTS + ptr_) * 8];
            k1f[mt][1] = *(const half8*)&k1t[((size_t)(2 + g) * MPTS + ptr_) * 8];
        }

        floatx16 acc[4];
        #pragma unroll
        for (int mt = 0; mt < 4; mt++)
            #pragma unroll
            for (int r = 0; r < 16; r++) acc[mt][r] = 0.0f;

        // ---- K-loop: 28 p-steps, 2 MFMA K-steps (qh) each; fully unrolled ----
        #pragma unroll
        for (int p4 = 0; p4 < 7; p4++) {
            #pragma unroll
            for (int pj = 0; pj < 4; pj++) {
                const int p = p4 * 4 + pj;
                const half8 bf0 = *(const half8*)&bs[bfo + p * 32];        // qh=0
                const half8 bf1 = *(const half8*)&bs[bfo + p * 32 + 16];   // qh=1
                #pragma unroll
                for (int mt = 0; mt < 4; mt++) {
                    const half8 af = k1f[mt][0] * k0v[mt][p4][pj];
                    acc[mt] = __builtin_amdgcn_mfma_f32_32x32x16_f16(
                        af, bf0, acc[mt], 0, 0, 0);
                }
                #pragma unroll
                for (int mt = 0; mt < 4; mt++) {
                    const half8 af = k1f[mt][1] * k0v[mt][p4][pj];
                    acc[mt] = __builtin_amdgcn_mfma_f32_32x32x16_f16(
                        af, bf1, acc[mt], 0, 0, 0);
                }
            }
        }

        // ---- epilogue: col = lane&31, row = (reg&3) + 8*(reg>>2) + 4*g ----
        #pragma unroll
        for (int mt = 0; mt < 4; mt++) {
            #pragma unroll
            for (int reg = 0; reg < 16; reg++) {
                const int row = (reg & 3) + 8 * (reg >> 2) + 4 * g;
                const size_t prow = (size_t)(chunkbase + mt * 32 + row);
                __builtin_nontemporal_store(acc[mt][reg],
                                            out + prow * FDIM + fbase + ln31);
            }
        }
    }
}

// ---------------------------------------------------------------------------
extern "C" void kernel_launch(void* const* d_in, const int* in_sizes, int n_in,
                              void* d_out, int out_size, void* d_ws, size_t ws_size,
                              hipStream_t stream) {
    const float* x     = (const float*)d_in[0];   // [8,16384,2]
    const float* sigma = (const float*)d_in[1];   // [1]
    const float* IF    = (const float*)d_in[2];   // [128,28,28]
    float* out = (float*)d_out;                   // [8,16384,128] fp32

    // d_ws layout: IFt 229,376 B @0; k0t 7,340,032 B @262,144; k1t 8,388,608 B next
    _Float16* IFt = (_Float16*)d_ws;
    _Float16* k0t = (_Float16*)((char*)d_ws + (256 << 10));
    _Float16* k1t = (_Float16*)((char*)d_ws + (256 << 10) + 7340032);

    prep_ift<<<(FDIM * KPAD) / 256, 256, 0, stream>>>(IF, IFt);       // 448 blocks
    prep_k<<<MPTS / 256, 256, 0, stream>>>(x, sigma, k0t, k1t);       // 512 blocks
    feats_kernel<<<512, 256, 0, stream>>>(IFt, k0t, k1t, out);        // 2 blocks/CU
}